// Round 2
// baseline (380.731 us; speedup 1.0000x reference)
//
#include <hip/hip_runtime.h>
#include <hip/hip_cooperative_groups.h>
#include <stdint.h>

namespace cg = cooperative_groups;

#define EPSV 1e-5f

typedef int v4i __attribute__((ext_vector_type(4)));

__device__ __forceinline__ v4i mfma16(v4i a, v4i b, v4i c) {
    return __builtin_amdgcn_mfma_i32_16x16x64_i8(a, b, c, 0, 0, 0);
}

// epilogue first stage: BN + ReLU-u4 quant -> r index in [0,15].
// (bit-exact same float sequence as original; second quant is a 16-entry LUT)
__device__ __forceinline__ int q_r(int s, float fscale, float inv, float beta,
                                   float s_relu)
{
#pragma clang fp contract(off)
    float y = (float)s * fscale;
    y = y * inv;
    y = y + beta;
    float r = rintf(y / s_relu);
    r = fminf(fmaxf(r, 0.f), 15.f);
    return (int)r;
}

// ---------------------------------------------------------------------------
// Per-tensor weight max-abs partials. grid (16, 9). No atomics, no memset:
// each block writes its own slot pmax[t*16 + bx].
// ---------------------------------------------------------------------------
struct WPtrs { const float* w[9]; int n[9]; };

__global__ __launch_bounds__(256) void k_wmax(WPtrs a, float* __restrict__ pmax)
{
    const int t = blockIdx.y;
    const int n = a.n[t];
    const float* w = a.w[t];
    float m = 0.f;
    for (int i = blockIdx.x * 256 + threadIdx.x; i < n; i += 16 * 256)
        m = fmaxf(m, fabsf(w[i]));
#pragma unroll
    for (int off = 32; off > 0; off >>= 1) m = fmaxf(m, __shfl_down(m, off));
    __shared__ float red[4];
    if ((threadIdx.x & 63) == 0) red[threadIdx.x >> 6] = m;
    __syncthreads();
    if (threadIdx.x == 0) {
        m = fmaxf(fmaxf(red[0], red[1]), fmaxf(red[2], red[3]));
        pmax[t * 16 + blockIdx.x] = m;
    }
}

__device__ __forceinline__ float wmax_of(const float* pmax, int L)
{
    float s = 0.f;
#pragma unroll
    for (int i = 0; i < 16; ++i) s = fmaxf(s, pmax[L * 16 + i]);
    return s;
}

// ---------------------------------------------------------------------------
// Pack kernel:
//  seg B    : conv weights -> MFMA B-fragment order (52992 dwords)
//  seg HEADF: head weights -> MFMA B-fragment order, NT=3 (768 dwords)
//  seg BN   : inv/beta (8*128 floats) + requant LUTs + final smax floats
// ---------------------------------------------------------------------------
struct PackArgs {
    const float* w[9];
    const float* bn[8];
    const float* sc;
    const float* pmax;
    float* smaxf;
    int* qw;
    float* bnp;
    int8_t* lut;
};

#define NB_B    207
#define NB_HEAD 3
#define NB_BN   3

__global__ __launch_bounds__(256) void k_pack(PackArgs a)
{
#pragma clang fp contract(off)
    const int blk = blockIdx.x;
    if (blk < NB_B) {
        const int u = blk * 256 + threadIdx.x;   // 0..52991 (exact)
        const int bcum[9] = {0, 256, 1792, 6912, 16128, 25344, 34560, 43776, 52992};
        const int CIGA[8] = {1, 4, 8, 16, 16, 16, 16, 16};
        const int COA[8]  = {16, 32, 64, 64, 64, 64, 64, 64};
        const int NTA[8]  = {1, 2, 4, 4, 4, 4, 4, 4};
        const int CINA[8] = {3, 16, 32, 64, 64, 64, 64, 64};
        int L = 0;
        while (u >= bcum[L + 1]) ++L;
        const int rem = u - bcum[L];
        const int d = rem & 3;
        const int lane = (rem >> 2) & 63;
        const int gnt = rem >> 8;
        const int NT = NTA[L];
        const int nt = gnt % NT;
        const int g = gnt / NT;
        const int CIG = CIGA[L], CIN = CINA[L], CO = COA[L];
        const int TG = 16 / CIG;
        const int n = nt * 16 + (lane & 15);
        const float s = wmax_of(a.pmax, L) / 7.0f;
        const float* w = a.w[L];
        unsigned dw = 0;
        for (int jb = 0; jb < 4; ++jb) {
            const int k = 16 * (lane >> 4) + 4 * d + jb;
            const int tap = g * TG + k / (4 * CIG);
            const int ci = k % (4 * CIG);
            int qv = 0;
            if (tap < 9 && ci < CIN && n < CO) {
                float rr = rintf(w[(n * CIN + ci) * 9 + tap] / s);
                rr = fminf(fmaxf(rr, -7.f), 7.f);
                qv = (int)rr;
            }
            dw |= ((unsigned)(qv & 0xff)) << (8 * jb);
        }
        a.qw[u] = (int)dw;
    } else if (blk < NB_B + NB_HEAD) {
        const int uh = (blk - NB_B) * 256 + threadIdx.x;  // 0..767 (exact)
        const int d = uh & 3;
        const int lane = (uh >> 2) & 63;
        const int nt = uh >> 8;                            // 0..2
        const int n = nt * 16 + (lane & 15);
        const float s = wmax_of(a.pmax, 8) / 7.0f;
        const float* w = a.w[8];
        unsigned dw = 0;
        for (int jb = 0; jb < 4; ++jb) {
            const int ci = 16 * (lane >> 4) + 4 * d + jb;   // K=64 = cin
            int qv = 0;
            if (n < 36) {
                float rr = rintf(w[n * 64 + ci] / s);
                rr = fminf(fmaxf(rr, -7.f), 7.f);
                qv = (int)rr;
            }
            dw |= ((unsigned)(qv & 0xff)) << (8 * jb);
        }
        a.qw[52992 + uh] = (int)dw;
    } else {
        const int id = (blk - NB_B - NB_HEAD) * 256 + threadIdx.x;
        if (id < 512) {
            const int l = id >> 6, c = id & 63;
            const int C[8] = {16, 32, 64, 64, 64, 64, 64, 64};
            if (c < C[l]) {
                const float* bn = a.bn[l];
                const int Cl = C[l];
                float g = bn[c], b = bn[Cl + c], m = bn[2 * Cl + c], v = bn[3 * Cl + c];
                float inv = g / sqrtf(v + EPSV);
                float mi = m * inv;
                a.bnp[l * 128 + c] = inv;
                a.bnp[l * 128 + 64 + c] = b - mi;
            }
        } else if (id < 656) {
            // requant LUTs. l=0..7: relu-u4 r -> next-layer signed code
            //               l=8   : conv0 input double-quant, idx = r0+8
            const int j = id - 512;
            const int l = j >> 4, r = j & 15;
            float code;
            if (l < 8) {
                const float s_relu = a.sc[10 + l];
                const float s_next = (l < 7) ? a.sc[2 + l] : a.sc[9];
                const float v = (float)r * s_relu;          // bit-exact: r*s_relu
                code = fminf(fmaxf(rintf(v / s_next), -8.f), 7.f);
            } else {
                const float v = (float)(r - 8) * a.sc[0];
                code = fminf(fmaxf(rintf(v / a.sc[1]), -8.f), 7.f);
            }
            a.lut[j] = (int8_t)(int)code;
        } else if (id < 665) {
            const int t = id - 656;
            a.smaxf[t] = wmax_of(a.pmax, t);
        }
    }
}

// ---------------------------------------------------------------------------
// L0 fused: fake-quant of fp32 x (NCHW) during tile staging (1 div + LUT) +
// MFMA conv 3->16ch + BN/ReLU-quant(LUT)/pool. out NHWC [16][160][320][16].
// grid (10, 40, 16); tile 10x66 px, CIG=1.
// ---------------------------------------------------------------------------
__global__ __launch_bounds__(256) void k_conv0(
    const float* __restrict__ x, int8_t* __restrict__ out,
    const int* __restrict__ bfrag, const float* __restrict__ scales,
    const float* __restrict__ smaxf, const float* __restrict__ bnp,
    const int8_t* __restrict__ luts)
{
#pragma clang fp contract(off)
    __shared__ int tile[660];        // 10 * 66
    __shared__ float bnl[128];
    __shared__ int8_t lc[32];        // [0..15] layer0 epi lut, [16..31] input lut

    const int b = blockIdx.z;
    const int py0 = blockIdx.y * 4;
    const int px0 = blockIdx.x * 32;
    const int ty0 = 2 * py0 - 1;
    const int tx0 = 2 * px0 - 1;
    const float s0 = scales[0];

    if (threadIdx.x < 16) lc[threadIdx.x] = luts[threadIdx.x];
    else if (threadIdx.x < 32) lc[threadIdx.x] = luts[128 + threadIdx.x - 16];
    if (threadIdx.x < 128) bnl[threadIdx.x] = bnp[threadIdx.x];
    __syncthreads();

    for (int i = threadIdx.x; i < 660; i += 256) {
        const int ly = i / 66;
        const int lx = i - ly * 66;
        const int gy = ty0 + ly, gx = tx0 + lx;
        int v = 0;
        if ((unsigned)gy < 320u && (unsigned)gx < 640u) {
#pragma unroll
            for (int ci = 0; ci < 3; ++ci) {
                float xv = x[((size_t)(b * 3 + ci) * 320 + gy) * 640 + gx];
                float r = rintf(xv / s0);
                r = fminf(fmaxf(r, -8.f), 7.f);
                v |= ((int)lc[16 + (int)r + 8] & 0xff) << (8 * ci);
            }
        }
        tile[i] = v;
    }

    const int lane = threadIdx.x & 63;
    const int wv = threadIdx.x >> 6;
    const v4i bfv = *(const v4i*)&bfrag[lane * 4];
    __syncthreads();

    const int q = lane >> 4;
    const int m = lane & 15;
    const int px_sub = m >> 2;
    const int op = m & 3;
    const int lyb = 2 * wv + (op >> 1);
    const int lxb0 = 2 * px_sub + (op & 1);

    const float sw = smaxf[0] / 7.0f;
    const float fscale = scales[1] * sw;
    const float s_relu = scales[10];
    const float inv = bnl[m];
    const float beta = bnl[64 + m];
    const int py = py0 + wv;

    for (int xs = 0; xs < 8; ++xs) {
        v4i af;
#pragma unroll
        for (int d = 0; d < 4; ++d) {
            int t = 4 * q + d; t = min(t, 8);
            const int ky = (t * 11) >> 5;
            const int kx = t - 3 * ky;
            af[d] = tile[(lyb + ky) * 66 + 8 * xs + lxb0 + kx];
        }
        v4i acc = mfma16(af, bfv, (v4i){0, 0, 0, 0});
        const int px = px0 + 4 * xs + q;
        const int s = max(max(acc[0], acc[1]), max(acc[2], acc[3]));
        const int ri = q_r(s, fscale, inv, beta, s_relu);
        out[((size_t)((b * 160 + py) * 320 + px)) * 16 + m] = lc[ri];
    }
}

// ---------------------------------------------------------------------------
// MFMA pool-conv block (L1..L3). NHWC int8 in/out. B fragments preloaded to
// regs when small, else staged to LDS. LUT requant. Vectorized b128 staging.
// ---------------------------------------------------------------------------
template <int CIG, int CO, int H, int W, int XL>
__global__ __launch_bounds__(256) void k_mconv(
    const int8_t* __restrict__ in, int8_t* __restrict__ out,
    const int* __restrict__ bfrag, const float* __restrict__ scales,
    const float* __restrict__ smaxf, const float* __restrict__ bnp,
    const int8_t* __restrict__ luts, int layer, int sin_idx, int srelu_idx)
{
#pragma clang fp contract(off)
    constexpr int NT = CO / 16;
    constexpr int TG = 16 / CIG;              // taps per K=64 group
    constexpr int NG = (9 + TG - 1) / TG;     // K groups
    constexpr int TLH = 2 * 4 + 2;            // NROWS=4, stride 2
    constexpr int TLW = 2 * 4 * XL + 2;
    constexpr int TILE_DW = TLH * TLW * CIG;
    constexpr bool PRELOAD = (NG * NT <= 8);
    constexpr int Ho = H / 2, Wo = W / 2;

    __shared__ int tile[TILE_DW];
    __shared__ float bnl[128];
    __shared__ int8_t lsh[16];
    __shared__ int bsh[PRELOAD ? 1 : NG * NT * 256];

    const int b = blockIdx.z;
    const int py0 = blockIdx.y * 4;
    const int px0 = blockIdx.x * (4 * XL);
    const int ty0 = 2 * py0 - 1;
    const int tx0 = 2 * px0 - 1;
    const int* gin = (const int*)in;

    // b128 staging: each 4-dword chunk lies within one pixel (CIG >= 4)
    for (int i = threadIdx.x; i < TILE_DW / 4; i += 256) {
        const int j = 4 * i;
        const int cig = j & (CIG - 1);
        const int rest = j / CIG;
        const int lx = rest % TLW;
        const int ly = rest / TLW;
        const int gy = ty0 + ly, gx = tx0 + lx;
        v4i v = {0, 0, 0, 0};
        if ((unsigned)gy < (unsigned)H && (unsigned)gx < (unsigned)W)
            v = *(const v4i*)&gin[((b * H + gy) * W + gx) * CIG + cig];
        *(v4i*)&tile[j] = v;
    }
    if (threadIdx.x < 128) bnl[threadIdx.x] = bnp[layer * 128 + threadIdx.x];
    if (threadIdx.x >= 128 && threadIdx.x < 144)
        lsh[threadIdx.x - 128] = luts[layer * 16 + threadIdx.x - 128];
    if constexpr (!PRELOAD) {
        for (int i = threadIdx.x; i < NG * NT * 256; i += 256) bsh[i] = bfrag[i];
    }

    const int lane = threadIdx.x & 63;
    const int wv = threadIdx.x >> 6;
    v4i breg[PRELOAD ? NG * NT : 1];
    if constexpr (PRELOAD) {
#pragma unroll
        for (int i = 0; i < NG * NT; ++i)
            breg[i] = *(const v4i*)&bfrag[(i * 64 + lane) * 4];
    }
    __syncthreads();

    const int q = lane >> 4;
    const int m = lane & 15;

    const float swv = smaxf[layer] / 7.0f;
    const float fscale = scales[sin_idx] * swv;
    const float s_relu = scales[srelu_idx];

    const int px_sub = m >> 2;
    const int op = m & 3;
    const int lyb = 2 * wv + (op >> 1);
    const int lxb0 = 2 * px_sub + (op & 1);
    const int py = py0 + wv;

    for (int xs = 0; xs < XL; ++xs) {
        v4i acc[NT];
#pragma unroll
        for (int j = 0; j < NT; ++j) acc[j] = (v4i){0, 0, 0, 0};

#pragma unroll
        for (int g = 0; g < NG; ++g) {
            v4i af;
            if constexpr (CIG == 16) {
                const int ky = (g * 11) >> 5;
                const int kx = g - 3 * ky;
                const int addr = ((lyb + ky) * TLW + (8 * xs + lxb0 + kx)) * 16 + 4 * q;
                af = *(const v4i*)&tile[addr];
            } else if constexpr (CIG == 8) {
                int t = 2 * g + (q >> 1); t = min(t, 8);
                const int ky = (t * 11) >> 5;
                const int kx = t - 3 * ky;
                const int addr = ((lyb + ky) * TLW + (8 * xs + lxb0 + kx)) * 8 + 4 * (q & 1);
                af = *(const v4i*)&tile[addr];
            } else {  // CIG == 4
                int t = 4 * g + q; t = min(t, 8);
                const int ky = (t * 11) >> 5;
                const int kx = t - 3 * ky;
                const int addr = ((lyb + ky) * TLW + (8 * xs + lxb0 + kx)) * 4;
                af = *(const v4i*)&tile[addr];
            }
#pragma unroll
            for (int j = 0; j < NT; ++j) {
                v4i bf;
                if constexpr (PRELOAD) bf = breg[g * NT + j];
                else bf = *(const v4i*)&bsh[((g * NT + j) * 64 + lane) * 4];
                acc[j] = mfma16(af, bf, acc[j]);
            }
        }

        const int px = px0 + 4 * xs + q;
        int8_t* po = out + ((size_t)((b * Ho + py) * Wo + px)) * CO + m;
#pragma unroll
        for (int j = 0; j < NT; ++j) {
            const int co = j * 16 + m;
            const int s = max(max(acc[j][0], acc[j][1]), max(acc[j][2], acc[j][3]));
            const int ri = q_r(s, fscale, bnl[co], bnl[64 + co], s_relu);
            po[j * 16] = lsh[ri];
        }
    }
}

// ---------------------------------------------------------------------------
// Cooperative tail: L4..L7 (20x40x64, 3x3 SAME, nonpool) + fused 1x1 head.
// grid (3,10,16) = 480 blocks, 256 thr — round-0's proven per-layer geometry,
// with grid.sync() replacing the 3 inter-layer kernel boundaries.
// B fragments read from global (L1/L2-hot), traffic spread over all CUs.
// ---------------------------------------------------------------------------
__global__ __launch_bounds__(256) void k_tail4(
    int8_t* __restrict__ bufA, int8_t* __restrict__ bufB,
    const int* __restrict__ qw, const float* __restrict__ scales,
    const float* __restrict__ smaxf, const float* __restrict__ bnp,
    const int8_t* __restrict__ luts, const int* __restrict__ hfrag,
    const float* __restrict__ b9, float* __restrict__ dout)
{
#pragma clang fp contract(off)
    cg::grid_group grid = cg::this_grid();
    constexpr int TLW = 18;
    constexpr int TILE_DW = 4 * TLW * 16;     // TLH=4, CIG=16
    __shared__ int tile[TILE_DW];
    __shared__ float bnl[128];
    __shared__ int8_t lsh[16];
    __shared__ int code_dw[512];              // 32 px x 16 dw, head A-frags

    const int b = blockIdx.z;
    const int py0 = blockIdx.y * 2;
    const int px0 = blockIdx.x * 16;
    const int ty0 = py0 - 1;
    const int tx0 = px0 - 1;
    const int lane = threadIdx.x & 63;
    const int wv = threadIdx.x >> 6;
    const int q = lane >> 4;
    const int m = lane & 15;
    const int wrow = wv >> 1;
    const int nt0 = (wv & 1) * 2;
    const int lyb = wrow;
    const int lxb0 = m;
    const int bo_[4] = {16128, 25344, 34560, 43776};

    for (int l = 0; l < 4; ++l) {
        if (l) grid.sync();
        const int8_t* in = (l & 1) ? bufB : bufA;
        int8_t* out = (l & 1) ? bufA : bufB;
        const int* gin = (const int*)in;

        for (int i = threadIdx.x; i < TILE_DW / 4; i += 256) {
            const int j = 4 * i;
            const int cig = j & 15;
            const int rest = j >> 4;
            const int lx = rest % TLW;
            const int ly = rest / TLW;
            const int gy = ty0 + ly, gx = tx0 + lx;
            v4i v = {0, 0, 0, 0};
            if ((unsigned)gy < 20u && (unsigned)gx < 40u)
                v = *(const v4i*)&gin[((b * 20 + gy) * 40 + gx) * 16 + cig];
            *(v4i*)&tile[j] = v;
        }
        if (threadIdx.x < 128) bnl[threadIdx.x] = bnp[(4 + l) * 128 + threadIdx.x];
        if (threadIdx.x >= 128 && threadIdx.x < 144)
            lsh[threadIdx.x - 128] = luts[(4 + l) * 16 + threadIdx.x - 128];
        __syncthreads();

        const int* bfrag = qw + bo_[l];
        const float fscale = scales[5 + l] * (smaxf[4 + l] / 7.0f);
        const float s_relu = scales[14 + l];

        v4i acc[2];
        acc[0] = (v4i){0, 0, 0, 0};
        acc[1] = (v4i){0, 0, 0, 0};
#pragma unroll
        for (int g = 0; g < 9; ++g) {
            const int ky = (g * 11) >> 5;
            const int kx = g - 3 * ky;
            const v4i af = *(const v4i*)&tile[((lyb + ky) * TLW + (lxb0 + kx)) * 16 + 4 * q];
#pragma unroll
            for (int jj = 0; jj < 2; ++jj) {
                const v4i bf = *(const v4i*)&bfrag[((g * 4 + nt0 + jj) * 64 + lane) * 4];
                acc[jj] = mfma16(af, bf, acc[jj]);
            }
        }

        const int py = py0 + wrow;
        if (l < 3) {
#pragma unroll
            for (int jj = 0; jj < 2; ++jj) {
                const int co = (nt0 + jj) * 16 + m;
                const float inv = bnl[co], beta = bnl[64 + co];
#pragma unroll
                for (int r = 0; r < 4; ++r) {
                    const int px = px0 + 4 * q + r;
                    if (px < 40) {
                        const int ri = q_r(acc[jj][r], fscale, inv, beta, s_relu);
                        out[((size_t)((b * 20 + py) * 40 + px)) * 64 + co] = lsh[ri];
                    }
                }
            }
        } else {
            // L7 codes -> LDS in head-A order, then fused 1x1 head
#pragma unroll
            for (int jj = 0; jj < 2; ++jj) {
                const int co = (nt0 + jj) * 16 + m;
                const float inv = bnl[co], beta = bnl[64 + co];
#pragma unroll
                for (int r = 0; r < 4; ++r) {
                    const int ri = q_r(acc[jj][r], fscale, inv, beta, s_relu);
                    ((int8_t*)code_dw)[(wrow * 16 + 4 * q + r) * 64 + co] = lsh[ri];
                }
            }
            __syncthreads();
            if (wv < 2) {
                const v4i ha = *(const v4i*)&code_dw[(wv * 16 + m) * 16 + 4 * q];
                const float fs = scales[9] * (smaxf[8] / 7.0f);
                const int py2 = py0 + wv;
#pragma unroll
                for (int nt = 0; nt < 3; ++nt) {
                    const v4i hb = *(const v4i*)&hfrag[(nt * 64 + lane) * 4];
                    const v4i hacc = mfma16(ha, hb, (v4i){0, 0, 0, 0});
                    const int co = nt * 16 + m;
                    if (co < 36) {
                        const float bias = b9[co];
#pragma unroll
                        for (int r = 0; r < 4; ++r) {
                            const int px = px0 + 4 * q + r;
                            if (px < 40) {
                                float yv = (float)hacc[r] * fs;
                                dout[((size_t)(b * 36 + co)) * 800 + py2 * 40 + px] = yv + bias;
                            }
                        }
                    }
                }
            }
        }
    }
}

// ---------------------------------------------------------------------------
// Launch: 7 dispatches (was 12)
// ---------------------------------------------------------------------------
extern "C" void kernel_launch(void* const* d_in, const int* in_sizes, int n_in,
                              void* d_out, int out_size, void* d_ws, size_t ws_size,
                              hipStream_t stream)
{
    const float* x = (const float*)d_in[0];
    const float* w[9];
    for (int i = 0; i < 9; i++) w[i] = (const float*)d_in[1 + i];
    const float* b9 = (const float*)d_in[10];
    const float* bn[8];
    for (int i = 0; i < 8; i++) bn[i] = (const float*)d_in[11 + i];
    const float* scales = (const float*)d_in[19];

    int8_t* base = (int8_t*)d_ws;
    int8_t* bufA = base;                             // 13,107,200 B
    int8_t* bufB = base + 13107200;                  // 13,107,200 B
    int*     qw  = (int*)(base + 26214400);          // 53760 dwords
    float*  pmax = (float*)(base + 26429440);        // 144 floats
    float* smaxf = (float*)(base + 26430016);        // 9 floats
    float*   bnp = (float*)(base + 26430080);        // 1024 floats
    int8_t* luts = base + 26434176;                  // 144 B

    static const int wn[9] = {432, 4608, 18432, 36864, 36864, 36864, 36864, 36864, 2304};

    WPtrs wp;
    for (int i = 0; i < 9; i++) { wp.w[i] = w[i]; wp.n[i] = wn[i]; }
    k_wmax<<<dim3(16, 9), 256, 0, stream>>>(wp, pmax);

    PackArgs pa;
    for (int i = 0; i < 9; i++) pa.w[i] = w[i];
    for (int i = 0; i < 8; i++) pa.bn[i] = bn[i];
    pa.sc = scales; pa.pmax = pmax; pa.smaxf = smaxf;
    pa.qw = qw; pa.bnp = bnp; pa.lut = luts;
    k_pack<<<NB_B + NB_HEAD + NB_BN, 256, 0, stream>>>(pa);

    // L0: fp32 x -> NHWC codes [16][160][320][16] in bufB
    k_conv0<<<dim3(10, 40, 16), 256, 0, stream>>>(
        x, bufB, qw, scales, smaxf, bnp, luts);

    // L1: CIG=4, CO=32, 160x320 -> 80x160
    k_mconv<4, 32, 160, 320, 4><<<dim3(10, 20, 16), 256, 0, stream>>>(
        bufB, bufA, qw + 256, scales, smaxf, bnp, luts, 1, 2, 11);
    // L2: CIG=8, CO=64, 80x160 -> 40x80
    k_mconv<8, 64, 80, 160, 2><<<dim3(10, 10, 16), 256, 0, stream>>>(
        bufA, bufB, qw + 1792, scales, smaxf, bnp, luts, 2, 3, 12);
    // L3: CIG=16, CO=64, 40x80 -> 20x40
    k_mconv<16, 64, 40, 80, 1><<<dim3(10, 5, 16), 256, 0, stream>>>(
        bufB, bufA, qw + 6912, scales, smaxf, bnp, luts, 3, 4, 13);

    // L4..L7 + head as ONE cooperative kernel (3 grid syncs)
    {
        int8_t* a0 = bufA; int8_t* b0 = bufB;
        const int* qwp = qw;
        const float* scp = scales;
        const float* smp = smaxf;
        const float* bnpp = bnp;
        const int8_t* lup = luts;
        const int* hfp = qw + 52992;
        const float* b9p = b9;
        float* dop = (float*)d_out;
        void* args[10] = {&a0, &b0, &qwp, &scp, &smp, &bnpp, &lup, &hfp, &b9p, &dop};
        hipLaunchCooperativeKernel((const void*)k_tail4, dim3(3, 10, 16), dim3(256),
                                   args, 0, stream);
    }

    (void)in_sizes; (void)n_in; (void)out_size; (void)ws_size;
}

// Round 3
// 207.195 us; speedup vs baseline: 1.8375x; 1.8375x over previous
//
#include <hip/hip_runtime.h>
#include <stdint.h>

#define EPSV 1e-5f

typedef int v4i __attribute__((ext_vector_type(4)));

__device__ __forceinline__ v4i mfma16(v4i a, v4i b, v4i c) {
    return __builtin_amdgcn_mfma_i32_16x16x64_i8(a, b, c, 0, 0, 0);
}

// epilogue first stage: BN + ReLU-u4 quant -> r index in [0,15].
// (bit-exact same float sequence as original; second quant is a 16-entry LUT)
__device__ __forceinline__ int q_r(int s, float fscale, float inv, float beta,
                                   float s_relu)
{
#pragma clang fp contract(off)
    float y = (float)s * fscale;
    y = y * inv;
    y = y + beta;
    float r = rintf(y / s_relu);
    r = fminf(fmaxf(r, 0.f), 15.f);
    return (int)r;
}

// ---------------------------------------------------------------------------
// Pack kernel (now also computes per-layer weight scale in-block; k_wmax is
// gone). Every B/head block lies entirely within one layer (all segment
// boundaries are multiples of 256), so the block scans its layer's weights
// (L2-hot) and reduces max|w| itself — bit-identical value (max is exact).
//  seg B    : conv weights -> MFMA B-fragment order (52992 dwords)
//  seg HEAD : head weights -> MFMA B-fragment order, NT=3 (768 dwords)
//  seg BN   : inv/beta (8*128 floats) + requant LUTs (144 int8)
// ---------------------------------------------------------------------------
struct PackArgs {
    const float* w[9];
    const float* bn[8];
    const float* sc;
    float* smaxf;
    int* qw;
    float* bnp;
    int8_t* lut;
};

#define NB_B    207
#define NB_HEAD 3
#define NB_BN   3

__global__ __launch_bounds__(256) void k_pack(PackArgs a)
{
#pragma clang fp contract(off)
    __shared__ float red[4];
    const int blk = blockIdx.x;
    if (blk < NB_B + NB_HEAD) {
        const int bcum[10] = {0, 256, 1792, 6912, 16128, 25344, 34560, 43776,
                              52992, 53760};
        const int wnn[9] = {432, 4608, 18432, 36864, 36864, 36864, 36864, 36864, 2304};
        const int u = blk * 256 + threadIdx.x;
        int L = 0;
        while (u >= bcum[L + 1]) ++L;          // uniform per block
        const float* w = a.w[L];
        const int n = wnn[L];

        // in-block layer max|w| (exact; order-independent)
        float mm = 0.f;
        for (int i = threadIdx.x; i < n; i += 256) mm = fmaxf(mm, fabsf(w[i]));
#pragma unroll
        for (int off = 32; off > 0; off >>= 1) mm = fmaxf(mm, __shfl_down(mm, off));
        if ((threadIdx.x & 63) == 0) red[threadIdx.x >> 6] = mm;
        __syncthreads();
        const float wmax = fmaxf(fmaxf(red[0], red[1]), fmaxf(red[2], red[3]));
        const float s = wmax / 7.0f;
        if (blk * 256 == bcum[L] && threadIdx.x == 0) a.smaxf[L] = wmax;

        if (L < 8) {
            const int CIGA[8] = {1, 4, 8, 16, 16, 16, 16, 16};
            const int COA[8]  = {16, 32, 64, 64, 64, 64, 64, 64};
            const int NTA[8]  = {1, 2, 4, 4, 4, 4, 4, 4};
            const int CINA[8] = {3, 16, 32, 64, 64, 64, 64, 64};
            const int rem = u - bcum[L];
            const int d = rem & 3;
            const int lane = (rem >> 2) & 63;
            const int gnt = rem >> 8;
            const int NT = NTA[L];
            const int nt = gnt % NT;
            const int g = gnt / NT;
            const int CIG = CIGA[L], CIN = CINA[L], CO = COA[L];
            const int TG = 16 / CIG;
            const int nn = nt * 16 + (lane & 15);
            unsigned dw = 0;
            for (int jb = 0; jb < 4; ++jb) {
                const int k = 16 * (lane >> 4) + 4 * d + jb;
                const int tap = g * TG + k / (4 * CIG);
                const int ci = k % (4 * CIG);
                int qv = 0;
                if (tap < 9 && ci < CIN && nn < CO) {
                    float rr = rintf(w[(nn * CIN + ci) * 9 + tap] / s);
                    rr = fminf(fmaxf(rr, -7.f), 7.f);
                    qv = (int)rr;
                }
                dw |= ((unsigned)(qv & 0xff)) << (8 * jb);
            }
            a.qw[u] = (int)dw;
        } else {
            const int uh = u - 52992;           // 0..767
            const int d = uh & 3;
            const int lane = (uh >> 2) & 63;
            const int nt = uh >> 8;             // 0..2
            const int nn = nt * 16 + (lane & 15);
            unsigned dw = 0;
            for (int jb = 0; jb < 4; ++jb) {
                const int ci = 16 * (lane >> 4) + 4 * d + jb;   // K=64 = cin
                int qv = 0;
                if (nn < 36) {
                    float rr = rintf(w[nn * 64 + ci] / s);
                    rr = fminf(fmaxf(rr, -7.f), 7.f);
                    qv = (int)rr;
                }
                dw |= ((unsigned)(qv & 0xff)) << (8 * jb);
            }
            a.qw[u] = (int)dw;
        }
    } else {
        const int id = (blk - NB_B - NB_HEAD) * 256 + threadIdx.x;
        if (id < 512) {
            const int l = id >> 6, c = id & 63;
            const int C[8] = {16, 32, 64, 64, 64, 64, 64, 64};
            if (c < C[l]) {
                const float* bn = a.bn[l];
                const int Cl = C[l];
                float g = bn[c], b = bn[Cl + c], m = bn[2 * Cl + c], v = bn[3 * Cl + c];
                float inv = g / sqrtf(v + EPSV);
                float mi = m * inv;
                a.bnp[l * 128 + c] = inv;
                a.bnp[l * 128 + 64 + c] = b - mi;
            }
        } else if (id < 656) {
            // requant LUTs. l=0..7: relu-u4 r -> next-layer signed code
            //               l=8   : conv0 input double-quant, idx = r0+8
            const int j = id - 512;
            const int l = j >> 4, r = j & 15;
            float code;
            if (l < 8) {
                const float s_relu = a.sc[10 + l];
                const float s_next = (l < 7) ? a.sc[2 + l] : a.sc[9];
                const float v = (float)r * s_relu;          // bit-exact: r*s_relu
                code = fminf(fmaxf(rintf(v / s_next), -8.f), 7.f);
            } else {
                const float v = (float)(r - 8) * a.sc[0];
                code = fminf(fmaxf(rintf(v / a.sc[1]), -8.f), 7.f);
            }
            a.lut[j] = (int8_t)(int)code;
        }
    }
}

// ---------------------------------------------------------------------------
// L0 fused: fake-quant of fp32 x (NCHW) during tile staging (1 div + LUT) +
// MFMA conv 3->16ch + BN/ReLU-quant(LUT)/pool. out NHWC [16][160][320][16].
// grid (10, 40, 16); tile 10x66 px, CIG=1.
// ---------------------------------------------------------------------------
__global__ __launch_bounds__(256) void k_conv0(
    const float* __restrict__ x, int8_t* __restrict__ out,
    const int* __restrict__ bfrag, const float* __restrict__ scales,
    const float* __restrict__ smaxf, const float* __restrict__ bnp,
    const int8_t* __restrict__ luts)
{
#pragma clang fp contract(off)
    __shared__ int tile[660];        // 10 * 66
    __shared__ float bnl[128];
    __shared__ int8_t lc[32];        // [0..15] layer0 epi lut, [16..31] input lut

    const int b = blockIdx.z;
    const int py0 = blockIdx.y * 4;
    const int px0 = blockIdx.x * 32;
    const int ty0 = 2 * py0 - 1;
    const int tx0 = 2 * px0 - 1;
    const float s0 = scales[0];

    if (threadIdx.x < 16) lc[threadIdx.x] = luts[threadIdx.x];
    else if (threadIdx.x < 32) lc[threadIdx.x] = luts[128 + threadIdx.x - 16];
    if (threadIdx.x < 128) bnl[threadIdx.x] = bnp[threadIdx.x];
    __syncthreads();

    for (int i = threadIdx.x; i < 660; i += 256) {
        const int ly = i / 66;
        const int lx = i - ly * 66;
        const int gy = ty0 + ly, gx = tx0 + lx;
        int v = 0;
        if ((unsigned)gy < 320u && (unsigned)gx < 640u) {
#pragma unroll
            for (int ci = 0; ci < 3; ++ci) {
                float xv = x[((size_t)(b * 3 + ci) * 320 + gy) * 640 + gx];
                float r = rintf(xv / s0);
                r = fminf(fmaxf(r, -8.f), 7.f);
                v |= ((int)lc[16 + (int)r + 8] & 0xff) << (8 * ci);
            }
        }
        tile[i] = v;
    }

    const int lane = threadIdx.x & 63;
    const int wv = threadIdx.x >> 6;
    const v4i bfv = *(const v4i*)&bfrag[lane * 4];
    __syncthreads();

    const int q = lane >> 4;
    const int m = lane & 15;
    const int px_sub = m >> 2;
    const int op = m & 3;
    const int lyb = 2 * wv + (op >> 1);
    const int lxb0 = 2 * px_sub + (op & 1);

    const float sw = smaxf[0] / 7.0f;
    const float fscale = scales[1] * sw;
    const float s_relu = scales[10];
    const float inv = bnl[m];
    const float beta = bnl[64 + m];
    const int py = py0 + wv;

    for (int xs = 0; xs < 8; ++xs) {
        v4i af;
#pragma unroll
        for (int d = 0; d < 4; ++d) {
            int t = 4 * q + d; t = min(t, 8);
            const int ky = (t * 11) >> 5;
            const int kx = t - 3 * ky;
            af[d] = tile[(lyb + ky) * 66 + 8 * xs + lxb0 + kx];
        }
        v4i acc = mfma16(af, bfv, (v4i){0, 0, 0, 0});
        const int px = px0 + 4 * xs + q;
        const int s = max(max(acc[0], acc[1]), max(acc[2], acc[3]));
        const int ri = q_r(s, fscale, inv, beta, s_relu);
        out[((size_t)((b * 160 + py) * 320 + px)) * 16 + m] = lc[ri];
    }
}

// ---------------------------------------------------------------------------
// MFMA pool-conv block (L1..L3). NHWC int8 in/out. B fragments preloaded to
// regs when small, else staged to LDS. LUT requant. Vectorized b128 staging.
// ---------------------------------------------------------------------------
template <int CIG, int CO, int H, int W, int XL>
__global__ __launch_bounds__(256) void k_mpool(
    const int8_t* __restrict__ in, int8_t* __restrict__ out,
    const int* __restrict__ bfrag, const float* __restrict__ scales,
    const float* __restrict__ smaxf, const float* __restrict__ bnp,
    const int8_t* __restrict__ luts, int layer, int sin_idx, int srelu_idx)
{
#pragma clang fp contract(off)
    constexpr int NT = CO / 16;
    constexpr int TG = 16 / CIG;              // taps per K=64 group
    constexpr int NG = (9 + TG - 1) / TG;     // K groups
    constexpr int TLH = 2 * 4 + 2;            // NROWS=4, stride 2
    constexpr int TLW = 2 * 4 * XL + 2;
    constexpr int TILE_DW = TLH * TLW * CIG;
    constexpr bool PRELOAD = (NG * NT <= 8);
    constexpr int Ho = H / 2, Wo = W / 2;

    __shared__ int tile[TILE_DW];
    __shared__ float bnl[128];
    __shared__ int8_t lsh[16];
    __shared__ int bsh[PRELOAD ? 1 : NG * NT * 256];

    const int b = blockIdx.z;
    const int py0 = blockIdx.y * 4;
    const int px0 = blockIdx.x * (4 * XL);
    const int ty0 = 2 * py0 - 1;
    const int tx0 = 2 * px0 - 1;
    const int* gin = (const int*)in;

    // b128 staging: each 4-dword chunk lies within one pixel (CIG >= 4)
    for (int i = threadIdx.x; i < TILE_DW / 4; i += 256) {
        const int j = 4 * i;
        const int cig = j & (CIG - 1);
        const int rest = j / CIG;
        const int lx = rest % TLW;
        const int ly = rest / TLW;
        const int gy = ty0 + ly, gx = tx0 + lx;
        v4i v = {0, 0, 0, 0};
        if ((unsigned)gy < (unsigned)H && (unsigned)gx < (unsigned)W)
            v = *(const v4i*)&gin[((b * H + gy) * W + gx) * CIG + cig];
        *(v4i*)&tile[j] = v;
    }
    if (threadIdx.x < 128) bnl[threadIdx.x] = bnp[layer * 128 + threadIdx.x];
    if (threadIdx.x >= 128 && threadIdx.x < 144)
        lsh[threadIdx.x - 128] = luts[layer * 16 + threadIdx.x - 128];
    if constexpr (!PRELOAD) {
        for (int i = threadIdx.x; i < NG * NT * 256; i += 256) bsh[i] = bfrag[i];
    }

    const int lane = threadIdx.x & 63;
    const int wv = threadIdx.x >> 6;
    v4i breg[PRELOAD ? NG * NT : 1];
    if constexpr (PRELOAD) {
#pragma unroll
        for (int i = 0; i < NG * NT; ++i)
            breg[i] = *(const v4i*)&bfrag[(i * 64 + lane) * 4];
    }
    __syncthreads();

    const int q = lane >> 4;
    const int m = lane & 15;

    const float fscale = scales[sin_idx] * (smaxf[layer] / 7.0f);
    const float s_relu = scales[srelu_idx];

    const int px_sub = m >> 2;
    const int op = m & 3;
    const int lyb = 2 * wv + (op >> 1);
    const int lxb0 = 2 * px_sub + (op & 1);
    const int py = py0 + wv;

    for (int xs = 0; xs < XL; ++xs) {
        v4i acc[NT];
#pragma unroll
        for (int j = 0; j < NT; ++j) acc[j] = (v4i){0, 0, 0, 0};

#pragma unroll
        for (int g = 0; g < NG; ++g) {
            v4i af;
            if constexpr (CIG == 16) {
                const int ky = (g * 11) >> 5;
                const int kx = g - 3 * ky;
                const int addr = ((lyb + ky) * TLW + (8 * xs + lxb0 + kx)) * 16 + 4 * q;
                af = *(const v4i*)&tile[addr];
            } else if constexpr (CIG == 8) {
                int t = 2 * g + (q >> 1); t = min(t, 8);
                const int ky = (t * 11) >> 5;
                const int kx = t - 3 * ky;
                const int addr = ((lyb + ky) * TLW + (8 * xs + lxb0 + kx)) * 8 + 4 * (q & 1);
                af = *(const v4i*)&tile[addr];
            } else {  // CIG == 4
                int t = 4 * g + q; t = min(t, 8);
                const int ky = (t * 11) >> 5;
                const int kx = t - 3 * ky;
                const int addr = ((lyb + ky) * TLW + (8 * xs + lxb0 + kx)) * 4;
                af = *(const v4i*)&tile[addr];
            }
#pragma unroll
            for (int j = 0; j < NT; ++j) {
                v4i bf;
                if constexpr (PRELOAD) bf = breg[g * NT + j];
                else bf = *(const v4i*)&bsh[((g * NT + j) * 64 + lane) * 4];
                acc[j] = mfma16(af, bf, acc[j]);
            }
        }

        const int px = px0 + 4 * xs + q;
        int8_t* po = out + ((size_t)((b * Ho + py) * Wo + px)) * CO + m;
#pragma unroll
        for (int j = 0; j < NT; ++j) {
            const int co = j * 16 + m;
            const int s = max(max(acc[j][0], acc[j][1]), max(acc[j][2], acc[j][3]));
            const int ri = q_r(s, fscale, bnl[co], bnl[64 + co], s_relu);
            po[j * 16] = lsh[ri];
        }
    }
}

// ---------------------------------------------------------------------------
// Tail conv (L4..L7): 20x40x64, 3x3 SAME, nonpool. Round-0-proven geometry:
// grid (3,10,16), 4 waves, 2 rows x 16 px per block, B frags from global
// (L2-hot). FUSED: append 1x1 head (64->36) + bias -> fp32 NCHW d_out.
// ---------------------------------------------------------------------------
template <bool FUSED>
__global__ __launch_bounds__(256) void k_mtail(
    const int8_t* __restrict__ in, int8_t* __restrict__ out,
    const int* __restrict__ bfrag, const float* __restrict__ scales,
    const float* __restrict__ smaxf, const float* __restrict__ bnp,
    const int8_t* __restrict__ luts, int layer, int sin_idx, int srelu_idx,
    const int* __restrict__ hfrag, const float* __restrict__ b9,
    float* __restrict__ dout)
{
#pragma clang fp contract(off)
    constexpr int TLW = 18;
    constexpr int TILE_DW = 4 * TLW * 16;
    __shared__ int tile[TILE_DW];
    __shared__ float bnl[128];
    __shared__ int8_t lsh[16];
    __shared__ int code_dw[FUSED ? 512 : 1];

    const int b = blockIdx.z;
    const int py0 = blockIdx.y * 2;
    const int px0 = blockIdx.x * 16;
    const int ty0 = py0 - 1;
    const int tx0 = px0 - 1;
    const int* gin = (const int*)in;

    for (int i = threadIdx.x; i < TILE_DW / 4; i += 256) {
        const int j = 4 * i;
        const int cig = j & 15;
        const int rest = j >> 4;
        const int lx = rest % TLW;
        const int ly = rest / TLW;
        const int gy = ty0 + ly, gx = tx0 + lx;
        v4i v = {0, 0, 0, 0};
        if ((unsigned)gy < 20u && (unsigned)gx < 40u)
            v = *(const v4i*)&gin[((b * 20 + gy) * 40 + gx) * 16 + cig];
        *(v4i*)&tile[j] = v;
    }
    if (threadIdx.x < 128) bnl[threadIdx.x] = bnp[layer * 128 + threadIdx.x];
    if (threadIdx.x >= 128 && threadIdx.x < 144)
        lsh[threadIdx.x - 128] = luts[layer * 16 + threadIdx.x - 128];
    __syncthreads();

    const int lane = threadIdx.x & 63;
    const int wv = threadIdx.x >> 6;
    const int q = lane >> 4;
    const int m = lane & 15;
    const int wrow = wv >> 1;
    const int nt0 = (wv & 1) * 2;

    const float fscale = scales[sin_idx] * (smaxf[layer] / 7.0f);
    const float s_relu = scales[srelu_idx];

    v4i acc[2];
    acc[0] = (v4i){0, 0, 0, 0};
    acc[1] = (v4i){0, 0, 0, 0};
#pragma unroll
    for (int g = 0; g < 9; ++g) {
        const int ky = (g * 11) >> 5;
        const int kx = g - 3 * ky;
        const v4i af = *(const v4i*)&tile[((wrow + ky) * TLW + (m + kx)) * 16 + 4 * q];
#pragma unroll
        for (int jj = 0; jj < 2; ++jj) {
            const v4i bf = *(const v4i*)&bfrag[((g * 4 + nt0 + jj) * 64 + lane) * 4];
            acc[jj] = mfma16(af, bf, acc[jj]);
        }
    }

    const int py = py0 + wrow;
#pragma unroll
    for (int jj = 0; jj < 2; ++jj) {
        const int co = (nt0 + jj) * 16 + m;
        const float inv = bnl[co], beta = bnl[64 + co];
#pragma unroll
        for (int r = 0; r < 4; ++r) {
            const int px = px0 + 4 * q + r;
            const int ri = q_r(acc[jj][r], fscale, inv, beta, s_relu);
            if constexpr (FUSED) {
                ((int8_t*)code_dw)[(wrow * 16 + 4 * q + r) * 64 + co] = lsh[ri];
            } else {
                if (px < 40)
                    out[((size_t)((b * 20 + py) * 40 + px)) * 64 + co] = lsh[ri];
            }
        }
    }

    if constexpr (FUSED) {
        __syncthreads();
        if (wv < 2) {
            const v4i ha = *(const v4i*)&code_dw[(wv * 16 + m) * 16 + 4 * q];
            const float fs = scales[9] * (smaxf[8] / 7.0f);
            const int py2 = py0 + wv;
#pragma unroll
            for (int nt = 0; nt < 3; ++nt) {
                const v4i hb = *(const v4i*)&hfrag[(nt * 64 + lane) * 4];
                const v4i hacc = mfma16(ha, hb, (v4i){0, 0, 0, 0});
                const int co = nt * 16 + m;
                if (co < 36) {
                    const float bias = b9[co];
#pragma unroll
                    for (int r = 0; r < 4; ++r) {
                        const int px = px0 + 4 * q + r;
                        if (px < 40) {
                            float yv = (float)hacc[r] * fs;
                            dout[((size_t)(b * 36 + co)) * 800 + py2 * 40 + px] = yv + bias;
                        }
                    }
                }
            }
        }
    }
}

// ---------------------------------------------------------------------------
// Launch: 9 regular dispatches (round 0 had 11 + memset; no cooperative)
// ---------------------------------------------------------------------------
extern "C" void kernel_launch(void* const* d_in, const int* in_sizes, int n_in,
                              void* d_out, int out_size, void* d_ws, size_t ws_size,
                              hipStream_t stream)
{
    const float* x = (const float*)d_in[0];
    const float* w[9];
    for (int i = 0; i < 9; i++) w[i] = (const float*)d_in[1 + i];
    const float* b9 = (const float*)d_in[10];
    const float* bn[8];
    for (int i = 0; i < 8; i++) bn[i] = (const float*)d_in[11 + i];
    const float* scales = (const float*)d_in[19];

    int8_t* base = (int8_t*)d_ws;
    int8_t* bufA = base;                             // 13,107,200 B
    int8_t* bufB = base + 13107200;                  // 13,107,200 B
    int*     qw  = (int*)(base + 26214400);          // 53760 dwords
    float* smaxf = (float*)(base + 26429440);        // 9 floats
    float*   bnp = (float*)(base + 26429504);        // 1024 floats
    int8_t* luts = base + 26433600;                  // 144 B

    PackArgs pa;
    for (int i = 0; i < 9; i++) pa.w[i] = w[i];
    for (int i = 0; i < 8; i++) pa.bn[i] = bn[i];
    pa.sc = scales; pa.smaxf = smaxf;
    pa.qw = qw; pa.bnp = bnp; pa.lut = luts;
    k_pack<<<NB_B + NB_HEAD + NB_BN, 256, 0, stream>>>(pa);

    // L0: fp32 x -> NHWC codes [16][160][320][16] in bufB
    k_conv0<<<dim3(10, 40, 16), 256, 0, stream>>>(
        x, bufB, qw, scales, smaxf, bnp, luts);

    // L1: CIG=4, CO=32, 160x320 -> 80x160
    k_mpool<4, 32, 160, 320, 4><<<dim3(10, 20, 16), 256, 0, stream>>>(
        bufB, bufA, qw + 256, scales, smaxf, bnp, luts, 1, 2, 11);
    // L2: CIG=8, CO=64, 80x160 -> 40x80
    k_mpool<8, 64, 80, 160, 2><<<dim3(10, 10, 16), 256, 0, stream>>>(
        bufA, bufB, qw + 1792, scales, smaxf, bnp, luts, 2, 3, 12);
    // L3: CIG=16, CO=64, 40x80 -> 20x40
    k_mpool<16, 64, 40, 80, 1><<<dim3(10, 5, 16), 256, 0, stream>>>(
        bufB, bufA, qw + 6912, scales, smaxf, bnp, luts, 3, 4, 13);

    // L4..L7 (+ fused head on L7), separate regular launches
    k_mtail<false><<<dim3(3, 10, 16), 256, 0, stream>>>(
        bufA, bufB, qw + 16128, scales, smaxf, bnp, luts, 4, 5, 14,
        nullptr, nullptr, nullptr);
    k_mtail<false><<<dim3(3, 10, 16), 256, 0, stream>>>(
        bufB, bufA, qw + 25344, scales, smaxf, bnp, luts, 5, 6, 15,
        nullptr, nullptr, nullptr);
    k_mtail<false><<<dim3(3, 10, 16), 256, 0, stream>>>(
        bufA, bufB, qw + 34560, scales, smaxf, bnp, luts, 6, 7, 16,
        nullptr, nullptr, nullptr);
    k_mtail<true><<<dim3(3, 10, 16), 256, 0, stream>>>(
        bufB, bufA, qw + 43776, scales, smaxf, bnp, luts, 7, 8, 17,
        qw + 52992, b9, (float*)d_out);

    (void)in_sizes; (void)n_in; (void)out_size; (void)ws_size;
}